// Round 12
// baseline (2231.587 us; speedup 1.0000x reference)
//
#include <hip/hip_runtime.h>
#include <stdint.h>

typedef _Float16 half_t;
typedef _Float16 half2_t __attribute__((ext_vector_type(2)));

#define TSEQ 2048
#define NB   32
#define HD   256
#define HN_ELEMS ((size_t)TSEQ*NB*HD)

static __device__ __forceinline__ float fdot2u(uint32_t a, uint32_t b, float acc) {
  return __builtin_amdgcn_fdot2(__builtin_bit_cast(half2_t, a),
                                __builtin_bit_cast(half2_t, b), acc, false);
}
static __device__ __forceinline__ int sdot4(uint32_t a, uint32_t b, int c) {
#if defined(__has_builtin)
#if __has_builtin(__builtin_amdgcn_sdot4)
  return __builtin_amdgcn_sdot4((int)a, (int)b, c, false);
#else
  int d;
  asm("v_dot4_i32_i8 %0, %1, %2, %3" : "=v"(d) : "v"(a), "v"(b), "v"(c));
  return d;
#endif
#else
  int d;
  asm("v_dot4_i32_i8 %0, %1, %2, %3" : "=v"(d) : "v"(a), "v"(b), "v"(c));
  return d;
#endif
}
static __device__ __forceinline__ float sigm_f(float x) {
  return __builtin_amdgcn_rcpf(1.0f + __expf(-x));
}
static __device__ __forceinline__ float tanh_f(float x) {
  return 2.0f * __builtin_amdgcn_rcpf(1.0f + __expf(-2.0f * x)) - 1.0f;
}
static __device__ __forceinline__ signed char q8(float v, float sc) {
  int q = (int)rintf(v * sc);
  q = q > 127 ? 127 : (q < -127 ? -127 : q);
  return (signed char)q;
}

// ---------------------------------------------------------------------------
// Prep: fold zx into W (f16) and zh into U (int8, fixed scale 127/(1/16)).
//  Wpk   : [kcG 0..31][1024 col][8 halfs]        (gemm reg loads)
//  Upk3b : i8 uint4 slots [slot][256 j][16 bytes]:
//          slot = c*16 + k/16        for gates c=0..2 (full K)
//          slot = 48 + k/16          for gate 3, k<128 (register half)
//  Ug4b  : gate 3, k>=128: [(k-128)/16][256 j][16 bytes]  (rec LDS tile)
// bias = bW+bU (added to gemm output); zero h/c state.
// ---------------------------------------------------------------------------
__global__ void prep_kernel(const float* __restrict__ W, const float* __restrict__ U,
                            const float* __restrict__ bW, const float* __restrict__ bU,
                            const float* __restrict__ zx, const float* __restrict__ zh,
                            half_t* __restrict__ Wpk, signed char* __restrict__ Upk3b,
                            signed char* __restrict__ Ug4b, float* __restrict__ bias,
                            half_t* __restrict__ hstate, float* __restrict__ cstate) {
  int tid = blockIdx.x * 256 + threadIdx.x;   // (kcG 0..31) x (n 0..1023)
  int n   = tid & 1023;
  int kcG = tid >> 10;
  #pragma unroll
  for (int e = 0; e < 8; ++e) {
    int k = kcG * 8 + e;
    Wpk[((size_t)kcG * 1024 + n) * 8 + e] = (half_t)(W[n * 256 + k] * zx[k]);
    float uv = U[n * 256 + k] * zh[k];
    signed char qv = q8(uv, 2032.0f);          // 127 / (1/16)
    int c = n >> 8, j = n & 255, q = k >> 4, by = k & 15;
    if (c < 3) {
      Upk3b[(((size_t)c * 16 + q) * 256 + j) * 16 + by] = qv;
    } else if (k < 128) {
      Upk3b[(((size_t)48 + q) * 256 + j) * 16 + by] = qv;
    } else {
      Ug4b[(((size_t)(q - 8)) * 256 + j) * 16 + by] = qv;
    }
  }
  if (kcG == 0) bias[n] = bW[n] + bU[n];
  if (tid < NB * HD) { hstate[tid] = (half_t)0.0f; cstate[tid] = 0.0f; }
}

// ---------------------------------------------------------------------------
// Input GEMM (R11, passing): block = 64 rows x 256 cols (one gate), 512 thr.
// ---------------------------------------------------------------------------
__global__ __launch_bounds__(512)
void gemm_kernel(const float* __restrict__ input, const uint4* __restrict__ Wpk,
                 const float* __restrict__ bias, half_t* __restrict__ gx, int row0,
                 uint32_t rz) {
  __shared__ __align__(16) uint4  As[64 * 32];    // 64 rows x 256 halfs = 32KB
  __shared__ __align__(16) float  part[8 * 256];  // 8KB
  __shared__ __align__(16) uint4  pad1b[1280];    // +20KB => 60KB: 2 blocks/CU
  const int tid = threadIdx.x;
  if ((int)blockIdx.x < 0) pad1b[tid] = As[tid];  // keep pad alive (never runs)
  const int cb    = blockIdx.x & 3;               // gate index
  const int rbase = (blockIdx.x >> 2) * 64;       // chunk-local row base
  const int jc    = tid & 255;
  const int kh    = tid >> 8;
  const int col   = cb * 256 + jc;

  uint32_t wreg[64];
  #pragma unroll
  for (int kc = 0; kc < 16; ++kc) {
    uint4 q = Wpk[(size_t)(kh * 16 + kc) * 1024 + col];
    wreg[kc * 4 + 0] = q.x ^ rz; wreg[kc * 4 + 1] = q.y ^ rz;
    wreg[kc * 4 + 2] = q.z ^ rz; wreg[kc * 4 + 3] = q.w ^ rz;
  }
  const float bc = bias[col];
  #pragma unroll
  for (int i = 0; i < 8; ++i) {
    int lin = tid + i * 512;
    int row = lin >> 6, f4 = lin & 63;
    float4 v = ((const float4*)input)[((size_t)(row0 + rbase + row)) * 64 + f4];
    half2_t p0; p0[0] = (half_t)v.x; p0[1] = (half_t)v.y;
    half2_t p1; p1[0] = (half_t)v.z; p1[1] = (half_t)v.w;
    ((uint2*)As)[row * 64 + f4] = make_uint2(__builtin_bit_cast(uint32_t, p0),
                                             __builtin_bit_cast(uint32_t, p1));
  }
  __syncthreads();

  #pragma unroll 1
  for (int rg = 0; rg < 64; rg += 8) {
    float acc[8];
    #pragma unroll
    for (int rr = 0; rr < 8; ++rr) {
      const uint4* arow = As + (rg + rr) * 32 + kh * 16;
      float a = 0.f;
      #pragma unroll
      for (int kc = 0; kc < 16; ++kc) {
        uint4 hv = arow[kc];                        // wave-uniform broadcast
        a = fdot2u(wreg[kc * 4 + 0], hv.x, a);
        a = fdot2u(wreg[kc * 4 + 1], hv.y, a);
        a = fdot2u(wreg[kc * 4 + 2], hv.z, a);
        a = fdot2u(wreg[kc * 4 + 3], hv.w, a);
      }
      acc[rr] = a;
    }
    if (kh) {
      #pragma unroll
      for (int rr = 0; rr < 8; ++rr) part[rr * 256 + jc] = acc[rr];
    }
    __syncthreads();
    if (!kh) {
      #pragma unroll
      for (int rr = 0; rr < 8; ++rr) {
        float v = acc[rr] + part[rr * 256 + jc] + bc;
        gx[((size_t)(rbase + rg + rr) * HD + jc) * 4 + cb] = (half_t)v;
      }
    }
    __syncthreads();
  }
}

// ---------------------------------------------------------------------------
// Recurrent kernel v3 (int8, 256 threads): 1 block = 1 chain = 1 CU.
// Thread j owns column j, ALL 4 gates, FULL K=256:
//   gates i,f,o + first half of gate g: 224 resident U-VGPRs (budget
//   ~65536/256 = 256; the R1-R11 streaming came from 512thr's 128 budget)
//   gate g second half: 32KB LDS, lane-consecutive uint4 reads (32/CU/step)
//   h: 256 i8 in LDS, double-buffered, wave-uniform uint4 broadcast reads
// No partial exchange, all-thread update, ONE barrier per step.
// ---------------------------------------------------------------------------
__global__ __launch_bounds__(256)
void rec_kernel(const half_t* __restrict__ gx, const uint4* __restrict__ Upk3p,
                const uint4* __restrict__ Ug4p,
                half_t* __restrict__ hstate, float* __restrict__ cstate,
                float* __restrict__ out, int tbase, int TB, int last,
                uint32_t rz) {
  __shared__ __align__(16) uint4 uglds[8 * 256];       // gate-g high-K: 32KB
  __shared__ __align__(16) uint4 hb[2][16];            // h i8, double-buffered

  const int b = blockIdx.x;
  const int j = threadIdx.x;

  // stage gate-g high-K U into LDS (one-time, coalesced, linear)
  #pragma unroll
  for (int i = 0; i < 8; ++i) uglds[i * 256 + j] = Ug4p[i * 256 + j];

  // gates i,f,o full-K + gate g low-K: 224 u32 of packed i8
  uint32_t upk0[64], upk1[64], upk2[64], upk3[32];
  #pragma unroll
  for (int q = 0; q < 16; ++q) {
    uint4 v = Upk3p[((size_t)(0 * 16 + q)) * 256 + j];
    upk0[q * 4 + 0] = v.x ^ rz; upk0[q * 4 + 1] = v.y ^ rz;
    upk0[q * 4 + 2] = v.z ^ rz; upk0[q * 4 + 3] = v.w ^ rz;
  }
  #pragma unroll
  for (int q = 0; q < 16; ++q) {
    uint4 v = Upk3p[((size_t)(1 * 16 + q)) * 256 + j];
    upk1[q * 4 + 0] = v.x ^ rz; upk1[q * 4 + 1] = v.y ^ rz;
    upk1[q * 4 + 2] = v.z ^ rz; upk1[q * 4 + 3] = v.w ^ rz;
  }
  #pragma unroll
  for (int q = 0; q < 16; ++q) {
    uint4 v = Upk3p[((size_t)(2 * 16 + q)) * 256 + j];
    upk2[q * 4 + 0] = v.x ^ rz; upk2[q * 4 + 1] = v.y ^ rz;
    upk2[q * 4 + 2] = v.z ^ rz; upk2[q * 4 + 3] = v.w ^ rz;
  }
  #pragma unroll
  for (int q = 0; q < 8; ++q) {
    uint4 v = Upk3p[((size_t)(48 + q)) * 256 + j];
    upk3[q * 4 + 0] = v.x ^ rz; upk3[q * 4 + 1] = v.y ^ rz;
    upk3[q * 4 + 2] = v.z ^ rz; upk3[q * 4 + 3] = v.w ^ rz;
  }

  float cc = cstate[b * HD + j];
  float h0 = (float)hstate[b * HD + j];
  ((signed char*)hb[0])[j] = (signed char)(int)rintf(h0 * 127.0f);

  const uint2* gpn = (const uint2*)gx + (size_t)b * HD + j;   // t=0 row
  float* outp = out + ((size_t)tbase * NB + b) * HD + j;
  uint2 gpk = *gpn, npk = make_uint2(0, 0);
  gpn += (size_t)NB * HD;                          // points at t=1
  __syncthreads();

  const float s = 0.0625f / 16129.0f;              // sU * sh
  float hlastf = h0;
  #pragma unroll 1
  for (int t = 0; t < TB; ++t) {
    const int cur = t & 1, nxt = cur ^ 1;
    if (t + 1 < TB) npk = *gpn;                    // prefetch next x-gates
    gpn += (size_t)NB * HD;

    int a0 = 0, a1 = 0, a2 = 0, a3 = 0;
    const uint4* hp = hb[cur];
    const uint4* ugp = uglds + j;
    #pragma unroll
    for (int q = 0; q < 16; ++q) {
      uint4 hv = hp[q];                            // wave-uniform broadcast
      a0 = sdot4(upk0[q * 4 + 0], hv.x, a0);
      a0 = sdot4(upk0[q * 4 + 1], hv.y, a0);
      a0 = sdot4(upk0[q * 4 + 2], hv.z, a0);
      a0 = sdot4(upk0[q * 4 + 3], hv.w, a0);
      a1 = sdot4(upk1[q * 4 + 0], hv.x, a1);
      a1 = sdot4(upk1[q * 4 + 1], hv.y, a1);
      a1 = sdot4(upk1[q * 4 + 2], hv.z, a1);
      a1 = sdot4(upk1[q * 4 + 3], hv.w, a1);
      a2 = sdot4(upk2[q * 4 + 0], hv.x, a2);
      a2 = sdot4(upk2[q * 4 + 1], hv.y, a2);
      a2 = sdot4(upk2[q * 4 + 2], hv.z, a2);
      a2 = sdot4(upk2[q * 4 + 3], hv.w, a2);
      if (q < 8) {
        a3 = sdot4(upk3[q * 4 + 0], hv.x, a3);
        a3 = sdot4(upk3[q * 4 + 1], hv.y, a3);
        a3 = sdot4(upk3[q * 4 + 2], hv.z, a3);
        a3 = sdot4(upk3[q * 4 + 3], hv.w, a3);
      } else {
        uint4 ug = ugp[(q - 8) * 256];             // lane-consecutive
        a3 = sdot4(ug.x, hv.x, a3);
        a3 = sdot4(ug.y, hv.y, a3);
        a3 = sdot4(ug.z, hv.z, a3);
        a3 = sdot4(ug.w, hv.w, a3);
      }
    }
    half2_t g01 = __builtin_bit_cast(half2_t, gpk.x);
    half2_t g23 = __builtin_bit_cast(half2_t, gpk.y);
    float f0 = (float)a0 * s + (float)g01[0];
    float f1 = (float)a1 * s + (float)g01[1];
    float f2 = (float)a2 * s + (float)g23[0];
    float f3 = (float)a3 * s + (float)g23[1];
    float gi = sigm_f(f0), gf = sigm_f(f1), go = sigm_f(f2), gg = tanh_f(f3);
    cc = gf * cc + gi * gg;
    float h = go * tanh_f(cc);
    hlastf = h;
    ((signed char*)hb[nxt])[j] = (signed char)(int)rintf(h * 127.0f);
    *outp = h;
    if (last && t == TB - 1) {
      out[HN_ELEMS + (size_t)b * HD + j] = h;
      out[HN_ELEMS + (size_t)NB * HD + (size_t)b * HD + j] = cc;
    }
    gpk = npk;
    outp += (size_t)NB * HD;
    __syncthreads();                               // nxt h visible to all
  }
  hstate[b * HD + j] = (half_t)hlastf;
  cstate[b * HD + j] = cc;
}

// ---------------------------------------------------------------------------
extern "C" void kernel_launch(void* const* d_in, const int* in_sizes, int n_in,
                              void* d_out, int out_size, void* d_ws, size_t ws_size,
                              hipStream_t stream) {
  const float* input = (const float*)d_in[0];
  const float* zx    = (const float*)d_in[1];
  const float* zh    = (const float*)d_in[2];
  const float* W     = (const float*)d_in[3];
  const float* bW    = (const float*)d_in[4];
  const float* U     = (const float*)d_in[5];
  const float* bU    = (const float*)d_in[6];
  float* out = (float*)d_out;

  char* ws = (char*)d_ws;
  signed char* Upk3b = (signed char*)(ws);                  // 224 KB (56 slots)
  signed char* Ug4b  = (signed char*)(ws + (224 << 10));    // 32 KB
  uint4*  Wpk    = (uint4*)(ws + (256 << 10));              // 512 KB
  float*  bias   = (float*) (ws + (768 << 10));             // 4 KB
  half_t* hstate = (half_t*)(ws + (772 << 10));             // 16 KB
  float*  cstate = (float*) (ws + (788 << 10));             // 32 KB
  half_t* gx     = (half_t*)(ws + (1 << 20));               // TB*32*1024*2 B

  // runtime zero the compiler cannot see through (in_sizes[1] == 256 always;
  // 256 >> 9 == 0). Anti-remat insurance on the U/W register loads.
  uint32_t rz = (uint32_t)(in_sizes[1] >> 9);

  int TB = TSEQ;
  while (TB > 32 && (size_t)(1u << 20) + (size_t)TB * NB * 1024 * 2 > ws_size) TB >>= 1;

  prep_kernel<<<128, 256, 0, stream>>>(W, U, bW, bU, zx, zh,
                                       (half_t*)Wpk, Upk3b, Ug4b,
                                       bias, hstate, cstate);

  int nch = TSEQ / TB;
  for (int c = 0; c < nch; ++c) {
    int tbase = c * TB;
    gemm_kernel<<<(TB * NB / 64) * 4, 512, 0, stream>>>(input, Wpk, bias, gx,
                                                        tbase * NB, rz);
    rec_kernel<<<NB, 256, 0, stream>>>(gx, (const uint4*)Upk3b, (const uint4*)Ug4b,
                                       hstate, cstate, out,
                                       tbase, TB, (c == nch - 1) ? 1 : 0, rz);
  }
}

// Round 13
// 2138.780 us; speedup vs baseline: 1.0434x; 1.0434x over previous
//
#include <hip/hip_runtime.h>
#include <stdint.h>

typedef _Float16 half_t;
typedef _Float16 half2_t __attribute__((ext_vector_type(2)));

#define TSEQ 2048
#define NB   32
#define HD   256
#define HN_ELEMS ((size_t)TSEQ*NB*HD)

static __device__ __forceinline__ float fdot2u(uint32_t a, uint32_t b, float acc) {
  return __builtin_amdgcn_fdot2(__builtin_bit_cast(half2_t, a),
                                __builtin_bit_cast(half2_t, b), acc, false);
}
static __device__ __forceinline__ int sdot4(uint32_t a, uint32_t b, int c) {
#if defined(__has_builtin)
#if __has_builtin(__builtin_amdgcn_sdot4)
  return __builtin_amdgcn_sdot4((int)a, (int)b, c, false);
#else
  int d;
  asm("v_dot4_i32_i8 %0, %1, %2, %3" : "=v"(d) : "v"(a), "v"(b), "v"(c));
  return d;
#endif
#else
  int d;
  asm("v_dot4_i32_i8 %0, %1, %2, %3" : "=v"(d) : "v"(a), "v"(b), "v"(c));
  return d;
#endif
}
// sum across the lane<32 / lane>=32 halves: after the swap, x holds
// {a.lo, a.lo-vals} and y holds {a.hi-vals, a.hi}; x+y = full sum in ALL lanes.
static __device__ __forceinline__ int halfsum(int a) {
  int y;
  asm("v_mov_b32 %1, %0\n\t"
      "v_permlane32_swap_b32 %0, %1"
      : "+v"(a), "=&v"(y));
  return a + y;
}
static __device__ __forceinline__ float sigm_f(float x) {
  return __builtin_amdgcn_rcpf(1.0f + __expf(-x));
}
static __device__ __forceinline__ float tanh_f(float x) {
  return 2.0f * __builtin_amdgcn_rcpf(1.0f + __expf(-2.0f * x)) - 1.0f;
}
static __device__ __forceinline__ signed char q8(float v, float sc) {
  int q = (int)rintf(v * sc);
  q = q > 127 ? 127 : (q < -127 ? -127 : q);
  return (signed char)q;
}

// ---------------------------------------------------------------------------
// Prep (R11 layout): fold zx into W (f16) and zh into U (i8, scale 127/(1/16)).
//  Wpk   : [kcG 0..31][1024 col][8 halfs]                  (gemm reg loads)
//  Upk3b : gates 0..2 i8: [((c*2+kg)*8+q)*256+j][16 bytes] (rec packed regs)
//  Ug4b  : gate 3 i8:     [((kg*8+q)*256+j)][16 bytes]     (rec LDS tile)
// bias = bW+bU (added to gemm output); zero h/c state.
// ---------------------------------------------------------------------------
__global__ void prep_kernel(const float* __restrict__ W, const float* __restrict__ U,
                            const float* __restrict__ bW, const float* __restrict__ bU,
                            const float* __restrict__ zx, const float* __restrict__ zh,
                            half_t* __restrict__ Wpk, signed char* __restrict__ Upk3b,
                            signed char* __restrict__ Ug4b, float* __restrict__ bias,
                            half_t* __restrict__ hstate, float* __restrict__ cstate) {
  int tid = blockIdx.x * 256 + threadIdx.x;   // (kcG 0..31) x (n 0..1023)
  int n   = tid & 1023;
  int kcG = tid >> 10;
  #pragma unroll
  for (int e = 0; e < 8; ++e) {
    int k = kcG * 8 + e;
    Wpk[((size_t)kcG * 1024 + n) * 8 + e] = (half_t)(W[n * 256 + k] * zx[k]);
    float uv = U[n * 256 + k] * zh[k];
    signed char qv = q8(uv, 2032.0f);          // 127 / (1/16)
    int kg = k >> 7, kk = k & 127, q = kk >> 4, by = kk & 15;
    if (n < 768) {
      int c = n >> 8, j = n & 255;
      Upk3b[(((size_t)(c * 2 + kg) * 8 + q) * 256 + j) * 16 + by] = qv;
    } else {
      Ug4b[(((size_t)kg * 8 + q) * 256 + (n & 255)) * 16 + by] = qv;
    }
  }
  if (kcG == 0) bias[n] = bW[n] + bU[n];
  if (tid < NB * HD) { hstate[tid] = (half_t)0.0f; cstate[tid] = 0.0f; }
}

// ---------------------------------------------------------------------------
// Input GEMM (R11, passing): block = 64 rows x 256 cols (one gate), 512 thr.
// ---------------------------------------------------------------------------
__global__ __launch_bounds__(512)
void gemm_kernel(const float* __restrict__ input, const uint4* __restrict__ Wpk,
                 const float* __restrict__ bias, half_t* __restrict__ gx, int row0,
                 uint32_t rz) {
  __shared__ __align__(16) uint4  As[64 * 32];    // 64 rows x 256 halfs = 32KB
  __shared__ __align__(16) float  part[8 * 256];  // 8KB
  __shared__ __align__(16) uint4  pad1b[1280];    // +20KB => 60KB: 2 blocks/CU
  const int tid = threadIdx.x;
  if ((int)blockIdx.x < 0) pad1b[tid] = As[tid];  // keep pad alive (never runs)
  const int cb    = blockIdx.x & 3;               // gate index
  const int rbase = (blockIdx.x >> 2) * 64;       // chunk-local row base
  const int jc    = tid & 255;
  const int kh    = tid >> 8;
  const int col   = cb * 256 + jc;

  uint32_t wreg[64];
  #pragma unroll
  for (int kc = 0; kc < 16; ++kc) {
    uint4 q = Wpk[(size_t)(kh * 16 + kc) * 1024 + col];
    wreg[kc * 4 + 0] = q.x ^ rz; wreg[kc * 4 + 1] = q.y ^ rz;
    wreg[kc * 4 + 2] = q.z ^ rz; wreg[kc * 4 + 3] = q.w ^ rz;
  }
  const float bc = bias[col];
  #pragma unroll
  for (int i = 0; i < 8; ++i) {
    int lin = tid + i * 512;
    int row = lin >> 6, f4 = lin & 63;
    float4 v = ((const float4*)input)[((size_t)(row0 + rbase + row)) * 64 + f4];
    half2_t p0; p0[0] = (half_t)v.x; p0[1] = (half_t)v.y;
    half2_t p1; p1[0] = (half_t)v.z; p1[1] = (half_t)v.w;
    ((uint2*)As)[row * 64 + f4] = make_uint2(__builtin_bit_cast(uint32_t, p0),
                                             __builtin_bit_cast(uint32_t, p1));
  }
  __syncthreads();

  #pragma unroll 1
  for (int rg = 0; rg < 64; rg += 8) {
    float acc[8];
    #pragma unroll
    for (int rr = 0; rr < 8; ++rr) {
      const uint4* arow = As + (rg + rr) * 32 + kh * 16;
      float a = 0.f;
      #pragma unroll
      for (int kc = 0; kc < 16; ++kc) {
        uint4 hv = arow[kc];                        // wave-uniform broadcast
        a = fdot2u(wreg[kc * 4 + 0], hv.x, a);
        a = fdot2u(wreg[kc * 4 + 1], hv.y, a);
        a = fdot2u(wreg[kc * 4 + 2], hv.z, a);
        a = fdot2u(wreg[kc * 4 + 3], hv.w, a);
      }
      acc[rr] = a;
    }
    if (kh) {
      #pragma unroll
      for (int rr = 0; rr < 8; ++rr) part[rr * 256 + jc] = acc[rr];
    }
    __syncthreads();
    if (!kh) {
      #pragma unroll
      for (int rr = 0; rr < 8; ++rr) {
        float v = acc[rr] + part[rr * 256 + jc] + bc;
        gx[((size_t)(rbase + rg + rr) * HD + jc) * 4 + cb] = (half_t)v;
      }
    }
    __syncthreads();
  }
}

// ---------------------------------------------------------------------------
// Recurrent kernel v4 (int8, in-wave halves): 1 block = 1 chain = 1 CU.
// 512 threads = 8 waves; lane<32 owns K-half 0, lane>=32 owns K-half 1 of
// column j = wave*32 + (lane&31). Cross-half reduction is ONE VALU
// v_permlane32_swap_b32 per gate (no LDS, no barrier); the partial-exchange
// and its barrier are gone; update runs on ALL threads (redundant per half);
// h double-buffered in LDS -> ONE barrier per step.
// U: gates i,f,o resident (96 u32/thread, the measured ~128-reg cap allows
// ~96+temps); gate g in 64KB LDS, lane-consecutive b128 reads.
// ---------------------------------------------------------------------------
__global__ __launch_bounds__(512)
void rec_kernel(const half_t* __restrict__ gx, const uint4* __restrict__ Upk3p,
                const uint4* __restrict__ Ug4p,
                half_t* __restrict__ hstate, float* __restrict__ cstate,
                float* __restrict__ out, int tbase, int TB, int last,
                uint32_t rz) {
  __shared__ __align__(16) uint4 uglds[4096];          // gate-g U i8: 64KB
  __shared__ __align__(16) uint4 hb[2][16];            // h i8, double-buffered

  const int b    = blockIdx.x;
  const int tid  = threadIdx.x;
  const int lane = tid & 63;
  const int kg   = lane >> 5;                          // half-wave = K-half
  const int j    = (tid >> 6) * 32 + (lane & 31);

  // stage gate-g U into LDS (one-time, coalesced, linear)
  #pragma unroll
  for (int i = 0; i < 8; ++i) uglds[i * 512 + tid] = Ug4p[i * 512 + tid];

  // gates i,f,o packed i8 for this (j, K-half): 96 u32
  uint32_t u0[32], u1[32], u2[32];
  #pragma unroll
  for (int q = 0; q < 8; ++q) {
    uint4 v = Upk3p[((size_t)(0 * 2 + kg) * 8 + q) * 256 + j];
    u0[q * 4 + 0] = v.x ^ rz; u0[q * 4 + 1] = v.y ^ rz;
    u0[q * 4 + 2] = v.z ^ rz; u0[q * 4 + 3] = v.w ^ rz;
  }
  #pragma unroll
  for (int q = 0; q < 8; ++q) {
    uint4 v = Upk3p[((size_t)(1 * 2 + kg) * 8 + q) * 256 + j];
    u1[q * 4 + 0] = v.x ^ rz; u1[q * 4 + 1] = v.y ^ rz;
    u1[q * 4 + 2] = v.z ^ rz; u1[q * 4 + 3] = v.w ^ rz;
  }
  #pragma unroll
  for (int q = 0; q < 8; ++q) {
    uint4 v = Upk3p[((size_t)(2 * 2 + kg) * 8 + q) * 256 + j];
    u2[q * 4 + 0] = v.x ^ rz; u2[q * 4 + 1] = v.y ^ rz;
    u2[q * 4 + 2] = v.z ^ rz; u2[q * 4 + 3] = v.w ^ rz;
  }

  float cc = cstate[b * HD + j];
  float h0 = (float)hstate[b * HD + j];
  float hlastf = h0;
  if (kg == 0) ((signed char*)hb[0])[j] = (signed char)(int)rintf(h0 * 127.0f);

  const uint2* gpn = (const uint2*)gx + (size_t)b * HD + j;   // t=0 row
  float* outp = out + ((size_t)tbase * NB + b) * HD + j;
  uint2 gpk = *gpn, npk = make_uint2(0, 0);
  gpn += (size_t)NB * HD;                          // points at t=1
  __syncthreads();

  const float s = 0.0625f / 16129.0f;              // sU * sh
  #pragma unroll 1
  for (int t = 0; t < TB; ++t) {
    if (t + 1 < TB) npk = *gpn;                    // prefetch next x-gates
    gpn += (size_t)NB * HD;

    int a0 = 0, a1 = 0, a2 = 0, a3 = 0;
    const uint4* hp  = hb[t & 1] + (kg << 3);      // this K-half of h
    const uint4* ugp = uglds + (size_t)kg * 2048 + j;
    #pragma unroll
    for (int q = 0; q < 8; ++q) {
      uint4 hv = hp[q];                            // 2 uniform addrs per wave
      uint4 ug = ugp[q * 256];                     // lane-consecutive
      a0 = sdot4(u0[q * 4 + 0], hv.x, a0);
      a0 = sdot4(u0[q * 4 + 1], hv.y, a0);
      a0 = sdot4(u0[q * 4 + 2], hv.z, a0);
      a0 = sdot4(u0[q * 4 + 3], hv.w, a0);
      a1 = sdot4(u1[q * 4 + 0], hv.x, a1);
      a1 = sdot4(u1[q * 4 + 1], hv.y, a1);
      a1 = sdot4(u1[q * 4 + 2], hv.z, a1);
      a1 = sdot4(u1[q * 4 + 3], hv.w, a1);
      a2 = sdot4(u2[q * 4 + 0], hv.x, a2);
      a2 = sdot4(u2[q * 4 + 1], hv.y, a2);
      a2 = sdot4(u2[q * 4 + 2], hv.z, a2);
      a2 = sdot4(u2[q * 4 + 3], hv.w, a2);
      a3 = sdot4(ug.x, hv.x, a3);
      a3 = sdot4(ug.y, hv.y, a3);
      a3 = sdot4(ug.z, hv.z, a3);
      a3 = sdot4(ug.w, hv.w, a3);
    }
    // cross-half sums (VALU permlane, both halves get the full dot)
    a0 = halfsum(a0); a1 = halfsum(a1);
    a2 = halfsum(a2); a3 = halfsum(a3);

    half2_t g01 = __builtin_bit_cast(half2_t, gpk.x);
    half2_t g23 = __builtin_bit_cast(half2_t, gpk.y);
    float f0 = (float)a0 * s + (float)g01[0];
    float f1 = (float)a1 * s + (float)g01[1];
    float f2 = (float)a2 * s + (float)g23[0];
    float f3 = (float)a3 * s + (float)g23[1];
    float gi = sigm_f(f0), gf = sigm_f(f1), go = sigm_f(f2), gg = tanh_f(f3);
    cc = gf * cc + gi * gg;
    float h = go * tanh_f(cc);
    hlastf = h;
    if (kg == 0) {
      ((signed char*)hb[(t & 1) ^ 1])[j] = (signed char)(int)rintf(h * 127.0f);
      *outp = h;
      if (last && t == TB - 1) {
        out[HN_ELEMS + (size_t)b * HD + j] = h;
        out[HN_ELEMS + (size_t)NB * HD + (size_t)b * HD + j] = cc;
      }
    }
    gpk = npk;
    outp += (size_t)NB * HD;
    __syncthreads();                               // next-step h visible
  }
  if (kg == 0) {
    hstate[b * HD + j] = (half_t)hlastf;
    cstate[b * HD + j] = cc;
  }
}

// ---------------------------------------------------------------------------
extern "C" void kernel_launch(void* const* d_in, const int* in_sizes, int n_in,
                              void* d_out, int out_size, void* d_ws, size_t ws_size,
                              hipStream_t stream) {
  const float* input = (const float*)d_in[0];
  const float* zx    = (const float*)d_in[1];
  const float* zh    = (const float*)d_in[2];
  const float* W     = (const float*)d_in[3];
  const float* bW    = (const float*)d_in[4];
  const float* U     = (const float*)d_in[5];
  const float* bU    = (const float*)d_in[6];
  float* out = (float*)d_out;

  char* ws = (char*)d_ws;
  signed char* Upk3b = (signed char*)(ws);                  // 192 KB
  signed char* Ug4b  = (signed char*)(ws + (192 << 10));    // 64 KB
  uint4*  Wpk    = (uint4*)(ws + (256 << 10));              // 512 KB
  float*  bias   = (float*) (ws + (768 << 10));             // 4 KB
  half_t* hstate = (half_t*)(ws + (772 << 10));             // 16 KB
  float*  cstate = (float*) (ws + (788 << 10));             // 32 KB
  half_t* gx     = (half_t*)(ws + (1 << 20));               // TB*32*1024*2 B

  // runtime zero the compiler cannot see through (in_sizes[1] == 256 always;
  // 256 >> 9 == 0). Anti-remat insurance on the U/W register loads.
  uint32_t rz = (uint32_t)(in_sizes[1] >> 9);

  int TB = TSEQ;
  while (TB > 32 && (size_t)(1u << 20) + (size_t)TB * NB * 1024 * 2 > ws_size) TB >>= 1;

  prep_kernel<<<128, 256, 0, stream>>>(W, U, bW, bU, zx, zh,
                                       (half_t*)Wpk, Upk3b, Ug4b,
                                       bias, hstate, cstate);

  int nch = TSEQ / TB;
  for (int c = 0; c < nch; ++c) {
    int tbase = c * TB;
    gemm_kernel<<<(TB * NB / 64) * 4, 512, 0, stream>>>(input, Wpk, bias, gx,
                                                        tbase * NB, rz);
    rec_kernel<<<NB, 512, 0, stream>>>(gx, (const uint4*)Upk3b, (const uint4*)Ug4b,
                                       hstate, cstate, out,
                                       tbase, TB, (c == nch - 1) ? 1 : 0, rz);
  }
}